// Round 1
// baseline (882.108 us; speedup 1.0000x reference)
//
#include <hip/hip_runtime.h>
#include <math.h>

#define D 128
#define NRBF 20
#define NEDGES 250000
#define NNODES 25000
#define NGRAPHS 512
#define NATOMS 100

constexpr float RCUT = 10.0f;
constexpr float PI_F = 3.14159265358979323846f;

__device__ __forceinline__ float silu_f(float x) { return x / (1.0f + __expf(-x)); }

// ---------------------------------------------------------------------------
// phi_table[t][0:384] = silu(emb[t] @ phi_W1 + b1) @ phi_W2 + b2  (100 rows)
// ---------------------------------------------------------------------------
__global__ __launch_bounds__(128) void k_phi_table(
    const float* __restrict__ emb, const float* __restrict__ W1, const float* __restrict__ b1,
    const float* __restrict__ W2, const float* __restrict__ b2, float* __restrict__ phi_tab)
{
    __shared__ float s_in[D];
    __shared__ float s_hid[D];
    const int t = blockIdx.x;   // atom type
    const int j = threadIdx.x;  // 0..127
    s_in[j] = emb[t * D + j];
    __syncthreads();
    float acc = b1[j];
    for (int c = 0; c < D; ++c) acc = fmaf(s_in[c], W1[c * D + j], acc);
    s_hid[j] = silu_f(acc);
    __syncthreads();
    #pragma unroll
    for (int r = 0; r < 3; ++r) {
        const int col = r * D + j;
        float a2 = b2[col];
        for (int c = 0; c < D; ++c) a2 = fmaf(s_hid[c], W2[c * 384 + col], a2);
        phi_tab[t * 384 + col] = a2;
    }
}

// ---------------------------------------------------------------------------
// init: state = embedding[atom_types], state_vec = 0, graph_state = 0
// ---------------------------------------------------------------------------
__global__ void k_init(const float* __restrict__ emb, const int* __restrict__ atom_types,
                       float* __restrict__ state, float* __restrict__ sv, float* __restrict__ gs)
{
    const int stride = gridDim.x * blockDim.x;
    const int i0 = blockIdx.x * blockDim.x + threadIdx.x;
    for (int k = i0; k < NNODES * 3 * D; k += stride) sv[k] = 0.f;
    for (int k = i0; k < NGRAPHS * D; k += stride) gs[k] = 0.f;
    for (int k = i0; k < NNODES * D; k += stride) {
        const int n = k >> 7;
        const int c = k & 127;
        state[k] = emb[atom_types[n] * D + c];
    }
}

// ---------------------------------------------------------------------------
// Edge kernel: per edge, W_out channels 128..383 only (m1 is dead: state_vec==0)
//   pf[c] = phi_table[type][c] * ((rbf*fc) @ filt_W[:,c] + filt_b[c]*fc)
//   state[to][c-128]            += pf[c]           (c in 128..255)
//   state_vec[to][a][c-256]     += n[a]*pf[c]      (c in 256..383)
// ---------------------------------------------------------------------------
#define EPB 256
__global__ __launch_bounds__(256) void k_edge(
    const float* __restrict__ edge_vec, const int* __restrict__ node_from,
    const int* __restrict__ node_to, const int* __restrict__ atom_types,
    const float* __restrict__ filt_W, const float* __restrict__ filt_b,
    const float* __restrict__ phi_tab,
    float* __restrict__ state, float* __restrict__ sv)
{
    __shared__ __align__(16) float s_e[EPB][24];  // [0:20)=rbf*fc*invd, [20]=fc, [21:24)=normalized
    __shared__ int s_to[EPB];
    __shared__ int s_ty[EPB];
    const int t = threadIdx.x;
    const int e0 = blockIdx.x * EPB;
    const int e = e0 + t;
    if (e < NEDGES) {
        const float x = edge_vec[e * 3 + 0];
        const float y = edge_vec[e * 3 + 1];
        const float z = edge_vec[e * 3 + 2];
        const float d = sqrtf(x * x + y * y + z * z);
        const float inv = 1.0f / d;
        const float th = PI_F * d / RCUT;
        const float fc = (d < RCUT) ? 0.5f * (__cosf(th) + 1.0f) : 0.0f;
        const float sc = fc * inv;
        #pragma unroll
        for (int k = 0; k < NRBF; ++k)
            s_e[t][k] = __sinf((float)(k + 1) * th) * sc;
        s_e[t][20] = fc;
        s_e[t][21] = x * inv;
        s_e[t][22] = y * inv;
        s_e[t][23] = z * inv;
        s_to[t] = node_to[e];
        s_ty[t] = atom_types[node_from[e]];
    }
    __syncthreads();

    const int c = 128 + t;  // channel 128..383
    float fw[NRBF];
    #pragma unroll
    for (int k = 0; k < NRBF; ++k) fw[k] = filt_W[k * 384 + c];
    const float fb = filt_b[c];

    const int cnt = min(EPB, NEDGES - e0);
    for (int i = 0; i < cnt; ++i) {
        const float4* sp = (const float4*)&s_e[i][0];
        const float4 r0 = sp[0], r1 = sp[1], r2 = sp[2], r3 = sp[3], r4 = sp[4], r5 = sp[5];
        float acc = fb * r5.x;
        acc = fmaf(r0.x, fw[0], acc);  acc = fmaf(r0.y, fw[1], acc);
        acc = fmaf(r0.z, fw[2], acc);  acc = fmaf(r0.w, fw[3], acc);
        acc = fmaf(r1.x, fw[4], acc);  acc = fmaf(r1.y, fw[5], acc);
        acc = fmaf(r1.z, fw[6], acc);  acc = fmaf(r1.w, fw[7], acc);
        acc = fmaf(r2.x, fw[8], acc);  acc = fmaf(r2.y, fw[9], acc);
        acc = fmaf(r2.z, fw[10], acc); acc = fmaf(r2.w, fw[11], acc);
        acc = fmaf(r3.x, fw[12], acc); acc = fmaf(r3.y, fw[13], acc);
        acc = fmaf(r3.z, fw[14], acc); acc = fmaf(r3.w, fw[15], acc);
        acc = fmaf(r4.x, fw[16], acc); acc = fmaf(r4.y, fw[17], acc);
        acc = fmaf(r4.z, fw[18], acc); acc = fmaf(r4.w, fw[19], acc);
        const float pf = phi_tab[s_ty[i] * 384 + c] * acc;
        const int to = s_to[i];
        if (t < 128) {
            unsafeAtomicAdd(&state[to * D + t], pf);            // m2
        } else {
            float* b = sv + to * 3 * D + (t - 128);             // msg_vec = n ⊗ m3
            unsafeAtomicAdd(b,         r5.y * pf);
            unsafeAtomicAdd(b + 128,   r5.z * pf);
            unsafeAtomicAdd(b + 256,   r5.w * pf);
        }
    }
}

// ---------------------------------------------------------------------------
// Up/Vp GEMMs + UV/Vn epilogue. 16 nodes per block, 256 threads:
// thread (cg=t&15 -> 8 cols, ni=t>>4 -> node). Accums up[3][8], vp[3][8].
// ---------------------------------------------------------------------------
#define BNUV 16
__global__ __launch_bounds__(256) void k_uv(
    const float* __restrict__ sv, const float* __restrict__ U_W, const float* __restrict__ V_W,
    float* __restrict__ UVb, float* __restrict__ Vnb)
{
    __shared__ __align__(16) float s_sv[BNUV][388];
    __shared__ __align__(16) float s_u[32][128];
    __shared__ __align__(16) float s_v[32][128];
    const int t = threadIdx.x;
    const int cg = t & 15;
    const int ni = t >> 4;
    const int node0 = blockIdx.x * BNUV;

    for (int i = t * 4; i < BNUV * 384; i += 1024) {
        const int row = i / 384;
        const int col = i - row * 384;
        float4 v = make_float4(0.f, 0.f, 0.f, 0.f);
        if (node0 + row < NNODES) v = *(const float4*)(sv + (size_t)(node0 + row) * 384 + col);
        *(float4*)&s_sv[row][col] = v;
    }

    float up[3][8], vp[3][8];
    #pragma unroll
    for (int a = 0; a < 3; ++a)
        #pragma unroll
        for (int h = 0; h < 8; ++h) { up[a][h] = 0.f; vp[a][h] = 0.f; }

    for (int kt = 0; kt < 4; ++kt) {
        __syncthreads();
        for (int i = t * 4; i < 32 * 128; i += 1024) {
            const int row = i >> 7, col = i & 127;
            *(float4*)&s_u[row][col] = *(const float4*)(U_W + (kt * 32 + row) * 128 + col);
            *(float4*)&s_v[row][col] = *(const float4*)(V_W + (kt * 32 + row) * 128 + col);
        }
        __syncthreads();
        #pragma unroll 8
        for (int k = 0; k < 32; ++k) {
            const int cc = kt * 32 + k;
            const float4 ua = *(const float4*)&s_u[k][cg * 8];
            const float4 ub = *(const float4*)&s_u[k][cg * 8 + 4];
            const float4 va = *(const float4*)&s_v[k][cg * 8];
            const float4 vb = *(const float4*)&s_v[k][cg * 8 + 4];
            #pragma unroll
            for (int a = 0; a < 3; ++a) {
                const float x = s_sv[ni][a * 128 + cc];
                up[a][0] = fmaf(x, ua.x, up[a][0]); up[a][1] = fmaf(x, ua.y, up[a][1]);
                up[a][2] = fmaf(x, ua.z, up[a][2]); up[a][3] = fmaf(x, ua.w, up[a][3]);
                up[a][4] = fmaf(x, ub.x, up[a][4]); up[a][5] = fmaf(x, ub.y, up[a][5]);
                up[a][6] = fmaf(x, ub.z, up[a][6]); up[a][7] = fmaf(x, ub.w, up[a][7]);
                vp[a][0] = fmaf(x, va.x, vp[a][0]); vp[a][1] = fmaf(x, va.y, vp[a][1]);
                vp[a][2] = fmaf(x, va.z, vp[a][2]); vp[a][3] = fmaf(x, va.w, vp[a][3]);
                vp[a][4] = fmaf(x, vb.x, vp[a][4]); vp[a][5] = fmaf(x, vb.y, vp[a][5]);
                vp[a][6] = fmaf(x, vb.z, vp[a][6]); vp[a][7] = fmaf(x, vb.w, vp[a][7]);
            }
        }
    }

    const int n = node0 + ni;
    if (n < NNODES) {
        float uvr[8], vnr[8];
        #pragma unroll
        for (int h = 0; h < 8; ++h) {
            uvr[h] = up[0][h] * vp[0][h] + up[1][h] * vp[1][h] + up[2][h] * vp[2][h];
            vnr[h] = sqrtf(vp[0][h] * vp[0][h] + vp[1][h] * vp[1][h] + vp[2][h] * vp[2][h]);
        }
        float* uo = UVb + n * D + cg * 8;
        float* vo = Vnb + n * D + cg * 8;
        *(float4*)uo = *(float4*)&uvr[0];
        *(float4*)(uo + 4) = *(float4*)&uvr[4];
        *(float4*)vo = *(float4*)&vnr[0];
        *(float4*)(vo + 4) = *(float4*)&vnr[4];
    }
}

// ---------------------------------------------------------------------------
// upd-MLP + final state + graph segment-sum (a_vv dead: state_vec unused).
// h=[Vn,state] (K=256) -> hid=silu(h@W1+b1) (128) -> a_sv,a_ss (W2 cols 128..383)
// graph_state[g] += state + a_ss + UV*a_sv
// ---------------------------------------------------------------------------
#define BNM 16
__global__ __launch_bounds__(256) void k_mlp(
    const float* __restrict__ state, const float* __restrict__ UVb, const float* __restrict__ Vnb,
    const float* __restrict__ W1, const float* __restrict__ b1,
    const float* __restrict__ W2, const float* __restrict__ b2,
    const int* __restrict__ ngi, float* __restrict__ gs)
{
    __shared__ __align__(16) float s_h[BNM][260];
    __shared__ __align__(16) float s_hid[BNM][132];
    __shared__ __align__(16) float s_w[32][128];
    __shared__ __align__(16) float s_w2[32][256];
    const int t = threadIdx.x;
    const int cg = t & 15;
    const int ni = t >> 4;
    const int node0 = blockIdx.x * BNM;

    for (int i = t * 4; i < BNM * 256; i += 1024) {
        const int row = i >> 8, col = i & 255;
        const int n = node0 + row;
        float4 v = make_float4(0.f, 0.f, 0.f, 0.f);
        if (n < NNODES) {
            v = (col < 128) ? *(const float4*)(Vnb + n * D + col)
                            : *(const float4*)(state + n * D + (col - 128));
        }
        *(float4*)&s_h[row][col] = v;
    }

    float acc[8];
    #pragma unroll
    for (int h = 0; h < 8; ++h) acc[h] = b1[cg * 8 + h];

    for (int kt = 0; kt < 8; ++kt) {
        __syncthreads();
        for (int i = t * 4; i < 32 * 128; i += 1024) {
            const int row = i >> 7, col = i & 127;
            *(float4*)&s_w[row][col] = *(const float4*)(W1 + (kt * 32 + row) * 128 + col);
        }
        __syncthreads();
        #pragma unroll 8
        for (int k = 0; k < 32; ++k) {
            const float x = s_h[ni][kt * 32 + k];
            const float4 wa = *(const float4*)&s_w[k][cg * 8];
            const float4 wb = *(const float4*)&s_w[k][cg * 8 + 4];
            acc[0] = fmaf(x, wa.x, acc[0]); acc[1] = fmaf(x, wa.y, acc[1]);
            acc[2] = fmaf(x, wa.z, acc[2]); acc[3] = fmaf(x, wa.w, acc[3]);
            acc[4] = fmaf(x, wb.x, acc[4]); acc[5] = fmaf(x, wb.y, acc[5]);
            acc[6] = fmaf(x, wb.z, acc[6]); acc[7] = fmaf(x, wb.w, acc[7]);
        }
    }
    #pragma unroll
    for (int h = 0; h < 8; ++h) s_hid[ni][cg * 8 + h] = silu_f(acc[h]);

    float av[8], as[8];
    #pragma unroll
    for (int h = 0; h < 8; ++h) {
        av[h] = b2[128 + cg * 8 + h];
        as[h] = b2[256 + cg * 8 + h];
    }
    for (int kt = 0; kt < 4; ++kt) {
        __syncthreads();
        for (int i = t * 4; i < 32 * 256; i += 1024) {
            const int row = i >> 8, col = i & 255;
            *(float4*)&s_w2[row][col] = *(const float4*)(W2 + (kt * 32 + row) * 384 + 128 + col);
        }
        __syncthreads();
        #pragma unroll 8
        for (int k = 0; k < 32; ++k) {
            const float x = s_hid[ni][kt * 32 + k];
            const float4 wa = *(const float4*)&s_w2[k][cg * 8];
            const float4 wb = *(const float4*)&s_w2[k][cg * 8 + 4];
            const float4 wc = *(const float4*)&s_w2[k][128 + cg * 8];
            const float4 wd = *(const float4*)&s_w2[k][128 + cg * 8 + 4];
            av[0] = fmaf(x, wa.x, av[0]); av[1] = fmaf(x, wa.y, av[1]);
            av[2] = fmaf(x, wa.z, av[2]); av[3] = fmaf(x, wa.w, av[3]);
            av[4] = fmaf(x, wb.x, av[4]); av[5] = fmaf(x, wb.y, av[5]);
            av[6] = fmaf(x, wb.z, av[6]); av[7] = fmaf(x, wb.w, av[7]);
            as[0] = fmaf(x, wc.x, as[0]); as[1] = fmaf(x, wc.y, as[1]);
            as[2] = fmaf(x, wc.z, as[2]); as[3] = fmaf(x, wc.w, as[3]);
            as[4] = fmaf(x, wd.x, as[4]); as[5] = fmaf(x, wd.y, as[5]);
            as[6] = fmaf(x, wd.z, as[6]); as[7] = fmaf(x, wd.w, as[7]);
        }
    }

    const int n = node0 + ni;
    if (n < NNODES) {
        const int g = ngi[n] - ngi[0];
        float uvr[8];
        const float* uvp = UVb + n * D + cg * 8;
        *(float4*)&uvr[0] = *(const float4*)uvp;
        *(float4*)&uvr[4] = *(const float4*)(uvp + 4);
        float* grow = gs + g * D + cg * 8;
        #pragma unroll
        for (int h = 0; h < 8; ++h) {
            const float st = s_h[ni][128 + cg * 8 + h];
            const float val = st + as[h] + uvr[h] * av[h];
            unsafeAtomicAdd(grow + h, val);
        }
    }
}

// ---------------------------------------------------------------------------
// Readout: out[g] = silu(gs[g] @ out_W1 + b1) @ out_W2 + b2
// ---------------------------------------------------------------------------
__global__ __launch_bounds__(128) void k_out(
    const float* __restrict__ gs, const float* __restrict__ W1, const float* __restrict__ b1,
    const float* __restrict__ W2, const float* __restrict__ b2, float* __restrict__ out)
{
    __shared__ float s_g[D];
    __shared__ float s_part[2];
    const int g = blockIdx.x;
    const int j = threadIdx.x;
    s_g[j] = gs[g * D + j];
    __syncthreads();
    float acc = b1[j];
    for (int c = 0; c < D; ++c) acc = fmaf(s_g[c], W1[c * D + j], acc);
    float m = silu_f(acc) * W2[j];
    #pragma unroll
    for (int off = 32; off > 0; off >>= 1) m += __shfl_down(m, off);
    if ((j & 63) == 0) s_part[j >> 6] = m;
    __syncthreads();
    if (j == 0) out[g] = s_part[0] + s_part[1] + b2[0];
}

extern "C" void kernel_launch(void* const* d_in, const int* in_sizes, int n_in,
                              void* d_out, int out_size, void* d_ws, size_t ws_size,
                              hipStream_t stream) {
    const float* edge_vec  = (const float*)d_in[0];
    const float* embedding = (const float*)d_in[1];
    const float* phi_W1    = (const float*)d_in[2];
    const float* phi_b1    = (const float*)d_in[3];
    const float* phi_W2    = (const float*)d_in[4];
    const float* phi_b2    = (const float*)d_in[5];
    const float* filt_W    = (const float*)d_in[6];
    const float* filt_b    = (const float*)d_in[7];
    const float* upd_W1    = (const float*)d_in[8];
    const float* upd_b1    = (const float*)d_in[9];
    const float* upd_W2    = (const float*)d_in[10];
    const float* upd_b2    = (const float*)d_in[11];
    const float* out_W1    = (const float*)d_in[12];
    const float* out_b1    = (const float*)d_in[13];
    const float* out_W2    = (const float*)d_in[14];
    const float* out_b2    = (const float*)d_in[15];
    const float* U_W       = (const float*)d_in[16];
    const float* V_W       = (const float*)d_in[17];
    const int* atom_types  = (const int*)d_in[18];
    const int* node_from   = (const int*)d_in[19];
    const int* node_to     = (const int*)d_in[20];
    const int* ngi         = (const int*)d_in[21];
    float* out = (float*)d_out;

    float* ws = (float*)d_ws;
    float* phi_tab = ws;                         // 100*384      = 38400
    float* state   = phi_tab + NATOMS * 384;     // 25000*128    = 3.2e6
    float* sv      = state + NNODES * D;         // 25000*384    = 9.6e6
    float* UVb     = sv + NNODES * 3 * D;        // 25000*128
    float* Vnb     = UVb + NNODES * D;           // 25000*128
    float* gsb     = Vnb + NNODES * D;           // 512*128

    k_phi_table<<<NATOMS, 128, 0, stream>>>(embedding, phi_W1, phi_b1, phi_W2, phi_b2, phi_tab);
    k_init<<<4096, 256, 0, stream>>>(embedding, atom_types, state, sv, gsb);
    k_edge<<<(NEDGES + EPB - 1) / EPB, 256, 0, stream>>>(
        edge_vec, node_from, node_to, atom_types, filt_W, filt_b, phi_tab, state, sv);
    k_uv<<<(NNODES + BNUV - 1) / BNUV, 256, 0, stream>>>(sv, U_W, V_W, UVb, Vnb);
    k_mlp<<<(NNODES + BNM - 1) / BNM, 256, 0, stream>>>(
        state, UVb, Vnb, upd_W1, upd_b1, upd_W2, upd_b2, ngi, gsb);
    k_out<<<NGRAPHS, 128, 0, stream>>>(gsb, out_W1, out_b1, out_W2, out_b2, out);
}

// Round 2
// 631.843 us; speedup vs baseline: 1.3961x; 1.3961x over previous
//
#include <hip/hip_runtime.h>
#include <math.h>

#define D 128
#define NRBF 20
#define NEDGES 250000
#define NNODES 25000
#define NGRAPHS 512
#define NATOMS 100

constexpr float RCUT = 10.0f;
constexpr float PI_F = 3.14159265358979323846f;

__device__ __forceinline__ float silu_f(float x) { return x / (1.0f + __expf(-x)); }

// ---------------------------------------------------------------------------
// phi_table[t][0:384] = silu(emb[t] @ phi_W1 + b1) @ phi_W2 + b2  (100 rows)
// ---------------------------------------------------------------------------
__global__ __launch_bounds__(128) void k_phi_table(
    const float* __restrict__ emb, const float* __restrict__ W1, const float* __restrict__ b1,
    const float* __restrict__ W2, const float* __restrict__ b2, float* __restrict__ phi_tab)
{
    __shared__ float s_in[D];
    __shared__ float s_hid[D];
    const int t = blockIdx.x;   // atom type
    const int j = threadIdx.x;  // 0..127
    s_in[j] = emb[t * D + j];
    __syncthreads();
    float acc = b1[j];
    for (int c = 0; c < D; ++c) acc = fmaf(s_in[c], W1[c * D + j], acc);
    s_hid[j] = silu_f(acc);
    __syncthreads();
    #pragma unroll
    for (int r = 0; r < 3; ++r) {
        const int col = r * D + j;
        float a2 = b2[col];
        for (int c = 0; c < D; ++c) a2 = fmaf(s_hid[c], W2[c * 384 + col], a2);
        phi_tab[t * 384 + col] = a2;
    }
}

// ---------------------------------------------------------------------------
// zero: counts (ints) + graph_state
// ---------------------------------------------------------------------------
__global__ void k_zero(int* __restrict__ counts, float* __restrict__ gs)
{
    const int i = blockIdx.x * 256 + threadIdx.x;
    if (i < NNODES) counts[i] = 0;
    if (i < NGRAPHS * D) gs[i] = 0.f;
}

// ---------------------------------------------------------------------------
// histogram of node_to
// ---------------------------------------------------------------------------
__global__ void k_hist(const int* __restrict__ node_to, int* __restrict__ counts)
{
    const int e = blockIdx.x * 256 + threadIdx.x;
    if (e < NEDGES) atomicAdd(&counts[node_to[e]], 1);
}

// ---------------------------------------------------------------------------
// single-block exclusive scan of counts -> row_ptr; cursor copy (in counts buf)
// 1024 threads x 25 elements each (1000*25 == 25000 exactly)
// ---------------------------------------------------------------------------
__global__ __launch_bounds__(1024) void k_scan(int* __restrict__ counts,
                                               int* __restrict__ row_ptr)
{
    __shared__ int s[1024];
    const int t = threadIdx.x;
    const int base = t * 25;
    int sum = 0;
    for (int j = 0; j < 25; ++j) {
        const int idx = base + j;
        if (idx < NNODES) sum += counts[idx];
    }
    s[t] = sum;
    __syncthreads();
    for (int off = 1; off < 1024; off <<= 1) {
        int v = 0;
        if (t >= off) v = s[t - off];
        __syncthreads();
        if (t >= off) s[t] += v;
        __syncthreads();
    }
    int run = (t > 0) ? s[t - 1] : 0;   // exclusive prefix
    for (int j = 0; j < 25; ++j) {
        const int idx = base + j;
        if (idx < NNODES) {
            const int v = counts[idx];
            row_ptr[idx] = run;
            counts[idx] = run;          // cursor = row start
            run += v;
        }
    }
    if (t == 1023) row_ptr[NNODES] = s[1023];
}

// ---------------------------------------------------------------------------
// per-edge precompute + scatter into CSR slot:
// edata[slot][0:20)=rbf*fc/d  [20]=fc  [21:24)=normalized ; ety[slot]=type(from)
// ---------------------------------------------------------------------------
__global__ __launch_bounds__(256) void k_pre(
    const float* __restrict__ edge_vec, const int* __restrict__ node_from,
    const int* __restrict__ node_to, const int* __restrict__ atom_types,
    int* __restrict__ cursor, float* __restrict__ edata, int* __restrict__ ety)
{
    const int e = blockIdx.x * 256 + threadIdx.x;
    if (e >= NEDGES) return;
    const float x = edge_vec[e * 3 + 0];
    const float y = edge_vec[e * 3 + 1];
    const float z = edge_vec[e * 3 + 2];
    const float d = sqrtf(x * x + y * y + z * z);
    const float inv = 1.0f / d;
    const float th = PI_F * d / RCUT;
    const float fc = (d < RCUT) ? 0.5f * (__cosf(th) + 1.0f) : 0.0f;
    const float sc = fc * inv;

    float buf[24];
    #pragma unroll
    for (int k = 0; k < NRBF; ++k) buf[k] = __sinf((float)(k + 1) * th) * sc;
    buf[20] = fc;
    buf[21] = x * inv;
    buf[22] = y * inv;
    buf[23] = z * inv;

    const int slot = atomicAdd(&cursor[node_to[e]], 1);
    float* o = edata + (size_t)slot * 24;
    #pragma unroll
    for (int q = 0; q < 6; ++q) *(float4*)(o + q * 4) = *(float4*)&buf[q * 4];
    ety[slot] = atom_types[node_from[e]];
}

// ---------------------------------------------------------------------------
// Gather: each block owns NPB nodes; thread t owns channel 128+t.
// For each node: loop CSR edges, w = fb*fc + rbf.fw ; pf = phi_tab[ty][c]*w
//   t<128  : state[n][t]   = emb[type(n)][t] + sum pf            (m2)
//   t>=128 : sv[n][a][t-128] = sum n_a * pf                       (msg_vec)
// No atomics, plain coalesced stores; sv zero-init fused (plain overwrite).
// ---------------------------------------------------------------------------
#define NPB 8
__global__ __launch_bounds__(256) void k_gather(
    const int* __restrict__ row_ptr, const float* __restrict__ edata,
    const int* __restrict__ ety, const float* __restrict__ phi_tab,
    const float* __restrict__ filt_W, const float* __restrict__ filt_b,
    const float* __restrict__ emb, const int* __restrict__ atom_types,
    float* __restrict__ state, float* __restrict__ sv)
{
    const int t = threadIdx.x;
    const int c = 128 + t;
    float fw[NRBF];
    #pragma unroll
    for (int k = 0; k < NRBF; ++k) fw[k] = filt_W[k * 384 + c];
    const float fb = filt_b[c];

    #pragma unroll 1
    for (int ni = 0; ni < NPB; ++ni) {
        const int n = blockIdx.x * NPB + ni;
        const int r0 = row_ptr[n];
        const int r1 = row_ptr[n + 1];
        float a0 = 0.f, a1 = 0.f, a2 = 0.f;
        for (int i = r0; i < r1; ++i) {
            const float4* p = (const float4*)(edata + (size_t)i * 24);
            const float4 q0 = p[0], q1 = p[1], q2 = p[2], q3 = p[3], q4 = p[4], q5 = p[5];
            float w = fb * q5.x;
            w = fmaf(q0.x, fw[0], w);  w = fmaf(q0.y, fw[1], w);
            w = fmaf(q0.z, fw[2], w);  w = fmaf(q0.w, fw[3], w);
            w = fmaf(q1.x, fw[4], w);  w = fmaf(q1.y, fw[5], w);
            w = fmaf(q1.z, fw[6], w);  w = fmaf(q1.w, fw[7], w);
            w = fmaf(q2.x, fw[8], w);  w = fmaf(q2.y, fw[9], w);
            w = fmaf(q2.z, fw[10], w); w = fmaf(q2.w, fw[11], w);
            w = fmaf(q3.x, fw[12], w); w = fmaf(q3.y, fw[13], w);
            w = fmaf(q3.z, fw[14], w); w = fmaf(q3.w, fw[15], w);
            w = fmaf(q4.x, fw[16], w); w = fmaf(q4.y, fw[17], w);
            w = fmaf(q4.z, fw[18], w); w = fmaf(q4.w, fw[19], w);
            const float pf = phi_tab[ety[i] * 384 + c] * w;
            if (t < 128) {
                a0 += pf;
            } else {
                a0 = fmaf(q5.y, pf, a0);
                a1 = fmaf(q5.z, pf, a1);
                a2 = fmaf(q5.w, pf, a2);
            }
        }
        if (t < 128) {
            state[n * D + t] = emb[atom_types[n] * D + t] + a0;
        } else {
            float* b = sv + (size_t)n * 3 * D + (t - 128);
            b[0]   = a0;
            b[128] = a1;
            b[256] = a2;
        }
    }
}

// ---------------------------------------------------------------------------
// Up/Vp GEMMs + UV/Vn epilogue. 16 nodes per block, 256 threads.
// ---------------------------------------------------------------------------
#define BNUV 16
__global__ __launch_bounds__(256) void k_uv(
    const float* __restrict__ sv, const float* __restrict__ U_W, const float* __restrict__ V_W,
    float* __restrict__ UVb, float* __restrict__ Vnb)
{
    __shared__ __align__(16) float s_sv[BNUV][388];
    __shared__ __align__(16) float s_u[32][128];
    __shared__ __align__(16) float s_v[32][128];
    const int t = threadIdx.x;
    const int cg = t & 15;
    const int ni = t >> 4;
    const int node0 = blockIdx.x * BNUV;

    for (int i = t * 4; i < BNUV * 384; i += 1024) {
        const int row = i / 384;
        const int col = i - row * 384;
        float4 v = make_float4(0.f, 0.f, 0.f, 0.f);
        if (node0 + row < NNODES) v = *(const float4*)(sv + (size_t)(node0 + row) * 384 + col);
        *(float4*)&s_sv[row][col] = v;
    }

    float up[3][8], vp[3][8];
    #pragma unroll
    for (int a = 0; a < 3; ++a)
        #pragma unroll
        for (int h = 0; h < 8; ++h) { up[a][h] = 0.f; vp[a][h] = 0.f; }

    for (int kt = 0; kt < 4; ++kt) {
        __syncthreads();
        for (int i = t * 4; i < 32 * 128; i += 1024) {
            const int row = i >> 7, col = i & 127;
            *(float4*)&s_u[row][col] = *(const float4*)(U_W + (kt * 32 + row) * 128 + col);
            *(float4*)&s_v[row][col] = *(const float4*)(V_W + (kt * 32 + row) * 128 + col);
        }
        __syncthreads();
        #pragma unroll 8
        for (int k = 0; k < 32; ++k) {
            const int cc = kt * 32 + k;
            const float4 ua = *(const float4*)&s_u[k][cg * 8];
            const float4 ub = *(const float4*)&s_u[k][cg * 8 + 4];
            const float4 va = *(const float4*)&s_v[k][cg * 8];
            const float4 vb = *(const float4*)&s_v[k][cg * 8 + 4];
            #pragma unroll
            for (int a = 0; a < 3; ++a) {
                const float x = s_sv[ni][a * 128 + cc];
                up[a][0] = fmaf(x, ua.x, up[a][0]); up[a][1] = fmaf(x, ua.y, up[a][1]);
                up[a][2] = fmaf(x, ua.z, up[a][2]); up[a][3] = fmaf(x, ua.w, up[a][3]);
                up[a][4] = fmaf(x, ub.x, up[a][4]); up[a][5] = fmaf(x, ub.y, up[a][5]);
                up[a][6] = fmaf(x, ub.z, up[a][6]); up[a][7] = fmaf(x, ub.w, up[a][7]);
                vp[a][0] = fmaf(x, va.x, vp[a][0]); vp[a][1] = fmaf(x, va.y, vp[a][1]);
                vp[a][2] = fmaf(x, va.z, vp[a][2]); vp[a][3] = fmaf(x, va.w, vp[a][3]);
                vp[a][4] = fmaf(x, vb.x, vp[a][4]); vp[a][5] = fmaf(x, vb.y, vp[a][5]);
                vp[a][6] = fmaf(x, vb.z, vp[a][6]); vp[a][7] = fmaf(x, vb.w, vp[a][7]);
            }
        }
    }

    const int n = node0 + ni;
    if (n < NNODES) {
        float uvr[8], vnr[8];
        #pragma unroll
        for (int h = 0; h < 8; ++h) {
            uvr[h] = up[0][h] * vp[0][h] + up[1][h] * vp[1][h] + up[2][h] * vp[2][h];
            vnr[h] = sqrtf(vp[0][h] * vp[0][h] + vp[1][h] * vp[1][h] + vp[2][h] * vp[2][h]);
        }
        float* uo = UVb + n * D + cg * 8;
        float* vo = Vnb + n * D + cg * 8;
        *(float4*)uo = *(float4*)&uvr[0];
        *(float4*)(uo + 4) = *(float4*)&uvr[4];
        *(float4*)vo = *(float4*)&vnr[0];
        *(float4*)(vo + 4) = *(float4*)&vnr[4];
    }
}

// ---------------------------------------------------------------------------
// upd-MLP + final state + graph segment-sum (a_vv dead: state_vec unused).
// ---------------------------------------------------------------------------
#define BNM 16
__global__ __launch_bounds__(256) void k_mlp(
    const float* __restrict__ state, const float* __restrict__ UVb, const float* __restrict__ Vnb,
    const float* __restrict__ W1, const float* __restrict__ b1,
    const float* __restrict__ W2, const float* __restrict__ b2,
    const int* __restrict__ ngi, float* __restrict__ gs)
{
    __shared__ __align__(16) float s_h[BNM][260];
    __shared__ __align__(16) float s_hid[BNM][132];
    __shared__ __align__(16) float s_w[32][128];
    __shared__ __align__(16) float s_w2[32][256];
    const int t = threadIdx.x;
    const int cg = t & 15;
    const int ni = t >> 4;
    const int node0 = blockIdx.x * BNM;

    for (int i = t * 4; i < BNM * 256; i += 1024) {
        const int row = i >> 8, col = i & 255;
        const int n = node0 + row;
        float4 v = make_float4(0.f, 0.f, 0.f, 0.f);
        if (n < NNODES) {
            v = (col < 128) ? *(const float4*)(Vnb + n * D + col)
                            : *(const float4*)(state + n * D + (col - 128));
        }
        *(float4*)&s_h[row][col] = v;
    }

    float acc[8];
    #pragma unroll
    for (int h = 0; h < 8; ++h) acc[h] = b1[cg * 8 + h];

    for (int kt = 0; kt < 8; ++kt) {
        __syncthreads();
        for (int i = t * 4; i < 32 * 128; i += 1024) {
            const int row = i >> 7, col = i & 127;
            *(float4*)&s_w[row][col] = *(const float4*)(W1 + (kt * 32 + row) * 128 + col);
        }
        __syncthreads();
        #pragma unroll 8
        for (int k = 0; k < 32; ++k) {
            const float x = s_h[ni][kt * 32 + k];
            const float4 wa = *(const float4*)&s_w[k][cg * 8];
            const float4 wb = *(const float4*)&s_w[k][cg * 8 + 4];
            acc[0] = fmaf(x, wa.x, acc[0]); acc[1] = fmaf(x, wa.y, acc[1]);
            acc[2] = fmaf(x, wa.z, acc[2]); acc[3] = fmaf(x, wa.w, acc[3]);
            acc[4] = fmaf(x, wb.x, acc[4]); acc[5] = fmaf(x, wb.y, acc[5]);
            acc[6] = fmaf(x, wb.z, acc[6]); acc[7] = fmaf(x, wb.w, acc[7]);
        }
    }
    #pragma unroll
    for (int h = 0; h < 8; ++h) s_hid[ni][cg * 8 + h] = silu_f(acc[h]);

    float av[8], as[8];
    #pragma unroll
    for (int h = 0; h < 8; ++h) {
        av[h] = b2[128 + cg * 8 + h];
        as[h] = b2[256 + cg * 8 + h];
    }
    for (int kt = 0; kt < 4; ++kt) {
        __syncthreads();
        for (int i = t * 4; i < 32 * 256; i += 1024) {
            const int row = i >> 8, col = i & 255;
            *(float4*)&s_w2[row][col] = *(const float4*)(W2 + (kt * 32 + row) * 384 + 128 + col);
        }
        __syncthreads();
        #pragma unroll 8
        for (int k = 0; k < 32; ++k) {
            const float x = s_hid[ni][kt * 32 + k];
            const float4 wa = *(const float4*)&s_w2[k][cg * 8];
            const float4 wb = *(const float4*)&s_w2[k][cg * 8 + 4];
            const float4 wc = *(const float4*)&s_w2[k][128 + cg * 8];
            const float4 wd = *(const float4*)&s_w2[k][128 + cg * 8 + 4];
            av[0] = fmaf(x, wa.x, av[0]); av[1] = fmaf(x, wa.y, av[1]);
            av[2] = fmaf(x, wa.z, av[2]); av[3] = fmaf(x, wa.w, av[3]);
            av[4] = fmaf(x, wb.x, av[4]); av[5] = fmaf(x, wb.y, av[5]);
            av[6] = fmaf(x, wb.z, av[6]); av[7] = fmaf(x, wb.w, av[7]);
            as[0] = fmaf(x, wc.x, as[0]); as[1] = fmaf(x, wc.y, as[1]);
            as[2] = fmaf(x, wc.z, as[2]); as[3] = fmaf(x, wc.w, as[3]);
            as[4] = fmaf(x, wd.x, as[4]); as[5] = fmaf(x, wd.y, as[5]);
            as[6] = fmaf(x, wd.z, as[6]); as[7] = fmaf(x, wd.w, as[7]);
        }
    }

    const int n = node0 + ni;
    if (n < NNODES) {
        const int g = ngi[n] - ngi[0];
        float uvr[8];
        const float* uvp = UVb + n * D + cg * 8;
        *(float4*)&uvr[0] = *(const float4*)uvp;
        *(float4*)&uvr[4] = *(const float4*)(uvp + 4);
        float* grow = gs + g * D + cg * 8;
        #pragma unroll
        for (int h = 0; h < 8; ++h) {
            const float st = s_h[ni][128 + cg * 8 + h];
            const float val = st + as[h] + uvr[h] * av[h];
            unsafeAtomicAdd(grow + h, val);
        }
    }
}

// ---------------------------------------------------------------------------
// Readout: out[g] = silu(gs[g] @ out_W1 + b1) @ out_W2 + b2
// ---------------------------------------------------------------------------
__global__ __launch_bounds__(128) void k_out(
    const float* __restrict__ gs, const float* __restrict__ W1, const float* __restrict__ b1,
    const float* __restrict__ W2, const float* __restrict__ b2, float* __restrict__ out)
{
    __shared__ float s_g[D];
    __shared__ float s_part[2];
    const int g = blockIdx.x;
    const int j = threadIdx.x;
    s_g[j] = gs[g * D + j];
    __syncthreads();
    float acc = b1[j];
    for (int c = 0; c < D; ++c) acc = fmaf(s_g[c], W1[c * D + j], acc);
    float m = silu_f(acc) * W2[j];
    #pragma unroll
    for (int off = 32; off > 0; off >>= 1) m += __shfl_down(m, off);
    if ((j & 63) == 0) s_part[j >> 6] = m;
    __syncthreads();
    if (j == 0) out[g] = s_part[0] + s_part[1] + b2[0];
}

extern "C" void kernel_launch(void* const* d_in, const int* in_sizes, int n_in,
                              void* d_out, int out_size, void* d_ws, size_t ws_size,
                              hipStream_t stream) {
    const float* edge_vec  = (const float*)d_in[0];
    const float* embedding = (const float*)d_in[1];
    const float* phi_W1    = (const float*)d_in[2];
    const float* phi_b1    = (const float*)d_in[3];
    const float* phi_W2    = (const float*)d_in[4];
    const float* phi_b2    = (const float*)d_in[5];
    const float* filt_W    = (const float*)d_in[6];
    const float* filt_b    = (const float*)d_in[7];
    const float* upd_W1    = (const float*)d_in[8];
    const float* upd_b1    = (const float*)d_in[9];
    const float* upd_W2    = (const float*)d_in[10];
    const float* upd_b2    = (const float*)d_in[11];
    const float* out_W1    = (const float*)d_in[12];
    const float* out_b1    = (const float*)d_in[13];
    const float* out_W2    = (const float*)d_in[14];
    const float* out_b2    = (const float*)d_in[15];
    const float* U_W       = (const float*)d_in[16];
    const float* V_W       = (const float*)d_in[17];
    const int* atom_types  = (const int*)d_in[18];
    const int* node_from   = (const int*)d_in[19];
    const int* node_to     = (const int*)d_in[20];
    const int* ngi         = (const int*)d_in[21];
    float* out = (float*)d_out;

    // Workspace layout (19,303,936 floats total — identical footprint to the
    // passing round). The CSR/edata scratch region is dead after k_gather and
    // is re-used as UVb/Vnb for the node phase.
    float* ws = (float*)d_ws;
    float* phi_tab = ws;                               // 38,400
    float* state   = phi_tab + NATOMS * 384;           // 3,200,000
    float* sv      = state + NNODES * D;               // 9,600,000
    float* gsb     = sv + (size_t)NNODES * 3 * D;      // 65,536
    float* scratch = gsb + NGRAPHS * D;                // 6,400,000 floats region
    int*   row_ptr = (int*)scratch;                    // 25,001 ints
    int*   counts  = row_ptr + NNODES + 1;             // 25,000 ints (doubles as cursor)
    int*   ety     = counts + NNODES;                  // 250,000 ints
    float* edata   = scratch + 300004;                 // 6,000,000 floats (16B aligned)
    float* UVb     = scratch;                          // phase-2 alias
    float* Vnb     = scratch + NNODES * D;             // phase-2 alias

    k_phi_table<<<NATOMS, 128, 0, stream>>>(embedding, phi_W1, phi_b1, phi_W2, phi_b2, phi_tab);
    k_zero<<<(NGRAPHS * D + 255) / 256, 256, 0, stream>>>(counts, gsb);
    k_hist<<<(NEDGES + 255) / 256, 256, 0, stream>>>(node_to, counts);
    k_scan<<<1, 1024, 0, stream>>>(counts, row_ptr);
    k_pre<<<(NEDGES + 255) / 256, 256, 0, stream>>>(
        edge_vec, node_from, node_to, atom_types, counts, edata, ety);
    k_gather<<<NNODES / NPB, 256, 0, stream>>>(
        row_ptr, edata, ety, phi_tab, filt_W, filt_b, embedding, atom_types, state, sv);
    k_uv<<<(NNODES + BNUV - 1) / BNUV, 256, 0, stream>>>(sv, U_W, V_W, UVb, Vnb);
    k_mlp<<<(NNODES + BNM - 1) / BNM, 256, 0, stream>>>(
        state, UVb, Vnb, upd_W1, upd_b1, upd_W2, upd_b2, ngi, gsb);
    k_out<<<NGRAPHS, 128, 0, stream>>>(gsb, out_W1, out_b1, out_W2, out_b2, out);
}

// Round 4
// 422.984 us; speedup vs baseline: 2.0854x; 1.4938x over previous
//
#include <hip/hip_runtime.h>
#include <math.h>

#define D 128
#define NRBF 20
#define NEDGES 250000
#define NNODES 25000
#define NGRAPHS 512
#define NATOMS 100

constexpr float RCUT = 10.0f;
constexpr float PI_F = 3.14159265358979323846f;

__device__ __forceinline__ float silu_f(float x) { return x / (1.0f + __expf(-x)); }

// ---------------------------------------------------------------------------
// phi_table[t][0:384] = silu(emb[t] @ phi_W1 + b1) @ phi_W2 + b2  (100 rows)
// ---------------------------------------------------------------------------
__global__ __launch_bounds__(128) void k_phi_table(
    const float* __restrict__ emb, const float* __restrict__ W1, const float* __restrict__ b1,
    const float* __restrict__ W2, const float* __restrict__ b2, float* __restrict__ phi_tab)
{
    __shared__ float s_in[D];
    __shared__ float s_hid[D];
    const int t = blockIdx.x;
    const int j = threadIdx.x;
    s_in[j] = emb[t * D + j];
    __syncthreads();
    float acc = b1[j];
    for (int c = 0; c < D; ++c) acc = fmaf(s_in[c], W1[c * D + j], acc);
    s_hid[j] = silu_f(acc);
    __syncthreads();
    #pragma unroll
    for (int r = 0; r < 3; ++r) {
        const int col = r * D + j;
        float a2 = b2[col];
        for (int c = 0; c < D; ++c) a2 = fmaf(s_hid[c], W2[c * 384 + col], a2);
        phi_tab[t * 384 + col] = a2;
    }
}

__global__ void k_zero(int* __restrict__ counts, float* __restrict__ gs)
{
    const int i = blockIdx.x * 256 + threadIdx.x;
    if (i < NNODES) counts[i] = 0;
    if (i < NGRAPHS * D) gs[i] = 0.f;
}

__global__ void k_hist(const int* __restrict__ node_to, int* __restrict__ counts)
{
    const int e = blockIdx.x * 256 + threadIdx.x;
    if (e < NEDGES) atomicAdd(&counts[node_to[e]], 1);
}

// single-block exclusive scan of counts -> row_ptr; cursor copy (in counts buf)
__global__ __launch_bounds__(1024) void k_scan(int* __restrict__ counts,
                                               int* __restrict__ row_ptr)
{
    __shared__ int s[1024];
    const int t = threadIdx.x;
    const int base = t * 25;
    int sum = 0;
    for (int j = 0; j < 25; ++j) {
        const int idx = base + j;
        if (idx < NNODES) sum += counts[idx];
    }
    s[t] = sum;
    __syncthreads();
    for (int off = 1; off < 1024; off <<= 1) {
        int v = 0;
        if (t >= off) v = s[t - off];
        __syncthreads();
        if (t >= off) s[t] += v;
        __syncthreads();
    }
    int run = (t > 0) ? s[t - 1] : 0;
    for (int j = 0; j < 25; ++j) {
        const int idx = base + j;
        if (idx < NNODES) {
            const int v = counts[idx];
            row_ptr[idx] = run;
            counts[idx] = run;
            run += v;
        }
    }
    if (t == 1023) row_ptr[NNODES] = s[1023];
}

// per-edge precompute + scatter into CSR slot
__global__ __launch_bounds__(256) void k_pre(
    const float* __restrict__ edge_vec, const int* __restrict__ node_from,
    const int* __restrict__ node_to, const int* __restrict__ atom_types,
    int* __restrict__ cursor, float* __restrict__ edata, int* __restrict__ ety)
{
    const int e = blockIdx.x * 256 + threadIdx.x;
    if (e >= NEDGES) return;
    const float x = edge_vec[e * 3 + 0];
    const float y = edge_vec[e * 3 + 1];
    const float z = edge_vec[e * 3 + 2];
    const float d = sqrtf(x * x + y * y + z * z);
    const float inv = 1.0f / d;
    const float th = PI_F * d / RCUT;
    const float fc = (d < RCUT) ? 0.5f * (__cosf(th) + 1.0f) : 0.0f;
    const float sc = fc * inv;

    float buf[24];
    #pragma unroll
    for (int k = 0; k < NRBF; ++k) buf[k] = __sinf((float)(k + 1) * th) * sc;
    buf[20] = fc;
    buf[21] = x * inv;
    buf[22] = y * inv;
    buf[23] = z * inv;

    const int slot = atomicAdd(&cursor[node_to[e]], 1);
    float* o = edata + (size_t)slot * 24;
    #pragma unroll
    for (int q = 0; q < 6; ++q) *(float4*)(o + q * 4) = *(float4*)&buf[q * 4];
    ety[slot] = atom_types[node_from[e]];
}

// ---------------------------------------------------------------------------
// Gather: 128 threads, 8 nodes/block, thread t owns channels 128+t AND 256+t.
// ---------------------------------------------------------------------------
#define GNPB 8
__global__ __launch_bounds__(128) void k_gather(
    const int* __restrict__ row_ptr, const float* __restrict__ edata,
    const int* __restrict__ ety, const float* __restrict__ phi_tab,
    const float* __restrict__ filt_W, const float* __restrict__ filt_b,
    const float* __restrict__ emb, const int* __restrict__ atom_types,
    float* __restrict__ state, float* __restrict__ sv)
{
    const int t = threadIdx.x;
    const int c1 = 128 + t;   // m2 channel
    const int c2 = 256 + t;   // m3 channel
    float fw1[NRBF], fw2[NRBF];
    #pragma unroll
    for (int k = 0; k < NRBF; ++k) {
        fw1[k] = filt_W[k * 384 + c1];
        fw2[k] = filt_W[k * 384 + c2];
    }
    const float fb1 = filt_b[c1];
    const float fb2 = filt_b[c2];

    #pragma unroll 1
    for (int ni = 0; ni < GNPB; ++ni) {
        const int n = blockIdx.x * GNPB + ni;
        const int r0 = row_ptr[n];
        const int r1 = row_ptr[n + 1];
        float as0 = 0.f, av0 = 0.f, av1 = 0.f, av2 = 0.f;
        for (int i = r0; i < r1; ++i) {
            const float4* p = (const float4*)(edata + (size_t)i * 24);
            const float4 q0 = p[0], q1 = p[1], q2 = p[2], q3 = p[3], q4 = p[4], q5 = p[5];
            const int ty = ety[i];
            float w1 = fb1 * q5.x, w2 = fb2 * q5.x;
            w1 = fmaf(q0.x, fw1[0], w1);  w2 = fmaf(q0.x, fw2[0], w2);
            w1 = fmaf(q0.y, fw1[1], w1);  w2 = fmaf(q0.y, fw2[1], w2);
            w1 = fmaf(q0.z, fw1[2], w1);  w2 = fmaf(q0.z, fw2[2], w2);
            w1 = fmaf(q0.w, fw1[3], w1);  w2 = fmaf(q0.w, fw2[3], w2);
            w1 = fmaf(q1.x, fw1[4], w1);  w2 = fmaf(q1.x, fw2[4], w2);
            w1 = fmaf(q1.y, fw1[5], w1);  w2 = fmaf(q1.y, fw2[5], w2);
            w1 = fmaf(q1.z, fw1[6], w1);  w2 = fmaf(q1.z, fw2[6], w2);
            w1 = fmaf(q1.w, fw1[7], w1);  w2 = fmaf(q1.w, fw2[7], w2);
            w1 = fmaf(q2.x, fw1[8], w1);  w2 = fmaf(q2.x, fw2[8], w2);
            w1 = fmaf(q2.y, fw1[9], w1);  w2 = fmaf(q2.y, fw2[9], w2);
            w1 = fmaf(q2.z, fw1[10], w1); w2 = fmaf(q2.z, fw2[10], w2);
            w1 = fmaf(q2.w, fw1[11], w1); w2 = fmaf(q2.w, fw2[11], w2);
            w1 = fmaf(q3.x, fw1[12], w1); w2 = fmaf(q3.x, fw2[12], w2);
            w1 = fmaf(q3.y, fw1[13], w1); w2 = fmaf(q3.y, fw2[13], w2);
            w1 = fmaf(q3.z, fw1[14], w1); w2 = fmaf(q3.z, fw2[14], w2);
            w1 = fmaf(q3.w, fw1[15], w1); w2 = fmaf(q3.w, fw2[15], w2);
            w1 = fmaf(q4.x, fw1[16], w1); w2 = fmaf(q4.x, fw2[16], w2);
            w1 = fmaf(q4.y, fw1[17], w1); w2 = fmaf(q4.y, fw2[17], w2);
            w1 = fmaf(q4.z, fw1[18], w1); w2 = fmaf(q4.z, fw2[18], w2);
            w1 = fmaf(q4.w, fw1[19], w1); w2 = fmaf(q4.w, fw2[19], w2);
            const float pf1 = phi_tab[ty * 384 + c1] * w1;
            const float pf2 = phi_tab[ty * 384 + c2] * w2;
            as0 += pf1;
            av0 = fmaf(q5.y, pf2, av0);
            av1 = fmaf(q5.z, pf2, av1);
            av2 = fmaf(q5.w, pf2, av2);
        }
        state[n * D + t] = emb[atom_types[n] * D + t] + as0;
        float* b = sv + (size_t)n * 3 * D + t;
        b[0]   = av0;
        b[128] = av1;
        b[256] = av2;
    }
}

// ---------------------------------------------------------------------------
// k_uv: Up/Vp GEMMs + UV/Vn epilogue. 16 nodes/block, per-kt staged operands.
// Thread: cg=t&15 -> cols {cg*4..+3, 64+cg*4..+3}; ni=t>>4 -> node.
// ---------------------------------------------------------------------------
#define BNUV 16
__global__ __launch_bounds__(256) void k_uv(
    const float* __restrict__ sv, const float* __restrict__ U_W, const float* __restrict__ V_W,
    float* __restrict__ UVb, float* __restrict__ Vnb)
{
    __shared__ __align__(16) float s_sv[BNUV][3][36];
    __shared__ __align__(16) float s_u[32][128];
    __shared__ __align__(16) float s_v[32][128];
    const int t = threadIdx.x;
    const int cg = t & 15;
    const int ni = t >> 4;
    const int node0 = blockIdx.x * BNUV;

    float up[3][8], vp[3][8];
    #pragma unroll
    for (int a = 0; a < 3; ++a)
        #pragma unroll
        for (int h = 0; h < 8; ++h) { up[a][h] = 0.f; vp[a][h] = 0.f; }

    for (int kt = 0; kt < 4; ++kt) {
        __syncthreads();
        // stage weights: 1024 float4 each
        for (int i = t; i < 1024; i += 256) {
            const int row = i >> 5, col = (i & 31) * 4;
            *(float4*)&s_u[row][col] = *(const float4*)(U_W + (kt * 32 + row) * 128 + col);
            *(float4*)&s_v[row][col] = *(const float4*)(V_W + (kt * 32 + row) * 128 + col);
        }
        // stage sv slice: 16 nodes x 3 x 32 floats = 384 float4
        for (int i = t; i < 384; i += 256) {
            const int nd = i / 24;
            const int rem = i - nd * 24;
            const int a = rem >> 3, c4 = (rem & 7) * 4;
            float4 v = make_float4(0.f, 0.f, 0.f, 0.f);
            if (node0 + nd < NNODES)
                v = *(const float4*)(sv + (size_t)(node0 + nd) * 384 + a * 128 + kt * 32 + c4);
            *(float4*)&s_sv[nd][a][c4] = v;
        }
        __syncthreads();
        #pragma unroll 8
        for (int k = 0; k < 32; ++k) {
            const float xs0 = s_sv[ni][0][k];
            const float xs1 = s_sv[ni][1][k];
            const float xs2 = s_sv[ni][2][k];
            const float4 ua = *(const float4*)&s_u[k][cg * 4];
            const float4 ub = *(const float4*)&s_u[k][64 + cg * 4];
            const float4 va = *(const float4*)&s_v[k][cg * 4];
            const float4 vb = *(const float4*)&s_v[k][64 + cg * 4];
            #define UVSTEP(a, XV) \
                up[a][0] = fmaf(XV, ua.x, up[a][0]); up[a][1] = fmaf(XV, ua.y, up[a][1]); \
                up[a][2] = fmaf(XV, ua.z, up[a][2]); up[a][3] = fmaf(XV, ua.w, up[a][3]); \
                up[a][4] = fmaf(XV, ub.x, up[a][4]); up[a][5] = fmaf(XV, ub.y, up[a][5]); \
                up[a][6] = fmaf(XV, ub.z, up[a][6]); up[a][7] = fmaf(XV, ub.w, up[a][7]); \
                vp[a][0] = fmaf(XV, va.x, vp[a][0]); vp[a][1] = fmaf(XV, va.y, vp[a][1]); \
                vp[a][2] = fmaf(XV, va.z, vp[a][2]); vp[a][3] = fmaf(XV, va.w, vp[a][3]); \
                vp[a][4] = fmaf(XV, vb.x, vp[a][4]); vp[a][5] = fmaf(XV, vb.y, vp[a][5]); \
                vp[a][6] = fmaf(XV, vb.z, vp[a][6]); vp[a][7] = fmaf(XV, vb.w, vp[a][7]);
            UVSTEP(0, xs0) UVSTEP(1, xs1) UVSTEP(2, xs2)
            #undef UVSTEP
        }
    }

    const int n = node0 + ni;
    if (n < NNODES) {
        float uvr[8], vnr[8];
        #pragma unroll
        for (int h = 0; h < 8; ++h) {
            uvr[h] = up[0][h] * vp[0][h] + up[1][h] * vp[1][h] + up[2][h] * vp[2][h];
            vnr[h] = sqrtf(vp[0][h] * vp[0][h] + vp[1][h] * vp[1][h] + vp[2][h] * vp[2][h]);
        }
        float* uo = UVb + n * D;
        float* vo = Vnb + n * D;
        *(float4*)(uo + cg * 4)      = *(float4*)&uvr[0];
        *(float4*)(uo + 64 + cg * 4) = *(float4*)&uvr[4];
        *(float4*)(vo + cg * 4)      = *(float4*)&vnr[0];
        *(float4*)(vo + 64 + cg * 4) = *(float4*)&vnr[4];
    }
}

// ---------------------------------------------------------------------------
// k_mlp1: hid = silu([Vn,state] @ W1 + b1).  BN=64 nodes, 256 threads,
// thread tile 4 rows x 8 cols (cols cg*4 and 64+cg*4).
// ---------------------------------------------------------------------------
#define BN1 64
__global__ __launch_bounds__(256) void k_mlp1(
    const float* __restrict__ Vnb, const float* __restrict__ state,
    const float* __restrict__ W1, const float* __restrict__ b1,
    float* __restrict__ hid)
{
    __shared__ __align__(16) float s_h[BN1][36];
    __shared__ __align__(16) float s_w[32][128];
    const int t = threadIdx.x;
    const int cg = t & 15;
    const int rg = t >> 4;
    const int n0 = blockIdx.x * BN1;

    float acc[4][8];
    #pragma unroll
    for (int r = 0; r < 4; ++r)
        #pragma unroll
        for (int h = 0; h < 8; ++h)
            acc[r][h] = (h < 4) ? b1[cg * 4 + h] : b1[64 + cg * 4 + (h - 4)];

    for (int kt = 0; kt < 8; ++kt) {
        const float* src = (kt < 4) ? (Vnb + kt * 32) : (state + (kt - 4) * 32);
        __syncthreads();
        #pragma unroll
        for (int q = 0; q < 2; ++q) {
            const int i = t * 2 + q;          // 512 float4 slots
            const int row = i >> 3, c4 = (i & 7) * 4;
            float4 v = make_float4(0.f, 0.f, 0.f, 0.f);
            if (n0 + row < NNODES) v = *(const float4*)(src + (size_t)(n0 + row) * D + c4);
            *(float4*)&s_h[row][c4] = v;
        }
        #pragma unroll
        for (int q = 0; q < 4; ++q) {
            const int i = t + q * 256;        // 1024 float4 slots
            const int row = i >> 5, col = (i & 31) * 4;
            *(float4*)&s_w[row][col] = *(const float4*)(W1 + (kt * 32 + row) * 128 + col);
        }
        __syncthreads();
        #pragma unroll 8
        for (int k = 0; k < 32; ++k) {
            const float4 wa = *(const float4*)&s_w[k][cg * 4];
            const float4 wb = *(const float4*)&s_w[k][64 + cg * 4];
            #pragma unroll
            for (int r = 0; r < 4; ++r) {
                const float x = s_h[rg * 4 + r][k];
                acc[r][0] = fmaf(x, wa.x, acc[r][0]); acc[r][1] = fmaf(x, wa.y, acc[r][1]);
                acc[r][2] = fmaf(x, wa.z, acc[r][2]); acc[r][3] = fmaf(x, wa.w, acc[r][3]);
                acc[r][4] = fmaf(x, wb.x, acc[r][4]); acc[r][5] = fmaf(x, wb.y, acc[r][5]);
                acc[r][6] = fmaf(x, wb.z, acc[r][6]); acc[r][7] = fmaf(x, wb.w, acc[r][7]);
            }
        }
    }

    #pragma unroll
    for (int r = 0; r < 4; ++r) {
        const int n = n0 + rg * 4 + r;
        if (n < NNODES) {
            float lo[4], hi[4];
            #pragma unroll
            for (int h = 0; h < 4; ++h) { lo[h] = silu_f(acc[r][h]); hi[h] = silu_f(acc[r][h + 4]); }
            *(float4*)(hid + (size_t)n * D + cg * 4)      = *(float4*)lo;
            *(float4*)(hid + (size_t)n * D + 64 + cg * 4) = *(float4*)hi;
        }
    }
}

// ---------------------------------------------------------------------------
// k_mlp2: a[:,128:384] = hid @ W2[:,128:384] + b2[128:384]; epilogue
// val = state + a_ss + UV*a_sv -> graph segment-sum (run-combined atomics).
// ---------------------------------------------------------------------------
#define BN2 64
__global__ __launch_bounds__(256) void k_mlp2(
    const float* __restrict__ hid, const float* __restrict__ state,
    const float* __restrict__ UVb,
    const float* __restrict__ W2, const float* __restrict__ b2,
    const int* __restrict__ ngi, float* __restrict__ gs)
{
    __shared__ __align__(16) float s_h[BN2][36];
    __shared__ __align__(16) float s_w2[32][256];
    const int t = threadIdx.x;
    const int cg = t & 15;
    const int rg = t >> 4;
    const int n0 = blockIdx.x * BN2;

    float acc[4][16];
    #pragma unroll
    for (int r = 0; r < 4; ++r)
        #pragma unroll
        for (int g = 0; g < 4; ++g)
            #pragma unroll
            for (int h = 0; h < 4; ++h)
                acc[r][g * 4 + h] = b2[128 + g * 64 + cg * 4 + h];

    for (int kt = 0; kt < 4; ++kt) {
        __syncthreads();
        #pragma unroll
        for (int q = 0; q < 2; ++q) {
            const int i = t * 2 + q;
            const int row = i >> 3, c4 = (i & 7) * 4;
            float4 v = make_float4(0.f, 0.f, 0.f, 0.f);
            if (n0 + row < NNODES)
                v = *(const float4*)(hid + (size_t)(n0 + row) * D + kt * 32 + c4);
            *(float4*)&s_h[row][c4] = v;
        }
        #pragma unroll
        for (int q = 0; q < 8; ++q) {
            const int i = t + q * 256;        // 2048 float4 slots
            const int row = i >> 6, col = (i & 63) * 4;
            *(float4*)&s_w2[row][col] = *(const float4*)(W2 + (kt * 32 + row) * 384 + 128 + col);
        }
        __syncthreads();
        #pragma unroll 4
        for (int k = 0; k < 32; ++k) {
            const float4 w0 = *(const float4*)&s_w2[k][cg * 4];
            const float4 w1 = *(const float4*)&s_w2[k][64 + cg * 4];
            const float4 w2v = *(const float4*)&s_w2[k][128 + cg * 4];
            const float4 w3 = *(const float4*)&s_w2[k][192 + cg * 4];
            #pragma unroll
            for (int r = 0; r < 4; ++r) {
                const float x = s_h[rg * 4 + r][k];
                acc[r][0]  = fmaf(x, w0.x, acc[r][0]);  acc[r][1]  = fmaf(x, w0.y, acc[r][1]);
                acc[r][2]  = fmaf(x, w0.z, acc[r][2]);  acc[r][3]  = fmaf(x, w0.w, acc[r][3]);
                acc[r][4]  = fmaf(x, w1.x, acc[r][4]);  acc[r][5]  = fmaf(x, w1.y, acc[r][5]);
                acc[r][6]  = fmaf(x, w1.z, acc[r][6]);  acc[r][7]  = fmaf(x, w1.w, acc[r][7]);
                acc[r][8]  = fmaf(x, w2v.x, acc[r][8]); acc[r][9]  = fmaf(x, w2v.y, acc[r][9]);
                acc[r][10] = fmaf(x, w2v.z, acc[r][10]);acc[r][11] = fmaf(x, w2v.w, acc[r][11]);
                acc[r][12] = fmaf(x, w3.x, acc[r][12]); acc[r][13] = fmaf(x, w3.y, acc[r][13]);
                acc[r][14] = fmaf(x, w3.z, acc[r][14]); acc[r][15] = fmaf(x, w3.w, acc[r][15]);
            }
        }
    }

    // Epilogue. local cols 0..127 = a_sv, 128..255 = a_ss.
    const int g0 = ngi[0];
    int gprev = -1;
    float run[8];
    #pragma unroll
    for (int r = 0; r < 4; ++r) {
        const int n = n0 + rg * 4 + r;
        if (n >= NNODES) break;
        const int g = ngi[n] - g0;
        const float4 stA = *(const float4*)(state + (size_t)n * D + cg * 4);
        const float4 stB = *(const float4*)(state + (size_t)n * D + 64 + cg * 4);
        const float4 uvA = *(const float4*)(UVb + (size_t)n * D + cg * 4);
        const float4 uvB = *(const float4*)(UVb + (size_t)n * D + 64 + cg * 4);
        float val[8];
        val[0] = stA.x + acc[r][8]  + uvA.x * acc[r][0];
        val[1] = stA.y + acc[r][9]  + uvA.y * acc[r][1];
        val[2] = stA.z + acc[r][10] + uvA.z * acc[r][2];
        val[3] = stA.w + acc[r][11] + uvA.w * acc[r][3];
        val[4] = stB.x + acc[r][12] + uvB.x * acc[r][4];
        val[5] = stB.y + acc[r][13] + uvB.y * acc[r][5];
        val[6] = stB.z + acc[r][14] + uvB.z * acc[r][6];
        val[7] = stB.w + acc[r][15] + uvB.w * acc[r][7];
        if (g == gprev) {
            #pragma unroll
            for (int h = 0; h < 8; ++h) run[h] += val[h];
        } else {
            if (gprev >= 0) {
                float* grow = gs + (size_t)gprev * D;
                #pragma unroll
                for (int h = 0; h < 4; ++h) unsafeAtomicAdd(grow + cg * 4 + h, run[h]);
                #pragma unroll
                for (int h = 0; h < 4; ++h) unsafeAtomicAdd(grow + 64 + cg * 4 + h, run[h + 4]);
            }
            #pragma unroll
            for (int h = 0; h < 8; ++h) run[h] = val[h];
            gprev = g;
        }
    }
    if (gprev >= 0) {
        float* grow = gs + (size_t)gprev * D;
        #pragma unroll
        for (int h = 0; h < 4; ++h) unsafeAtomicAdd(grow + cg * 4 + h, run[h]);
        #pragma unroll
        for (int h = 0; h < 4; ++h) unsafeAtomicAdd(grow + 64 + cg * 4 + h, run[h + 4]);
    }
}

// ---------------------------------------------------------------------------
// Readout: out[g] = silu(gs[g] @ out_W1 + b1) @ out_W2 + b2
// ---------------------------------------------------------------------------
__global__ __launch_bounds__(128) void k_out(
    const float* __restrict__ gs, const float* __restrict__ W1, const float* __restrict__ b1,
    const float* __restrict__ W2, const float* __restrict__ b2, float* __restrict__ out)
{
    __shared__ float s_g[D];
    __shared__ float s_part[2];
    const int g = blockIdx.x;
    const int j = threadIdx.x;
    s_g[j] = gs[g * D + j];
    __syncthreads();
    float acc = b1[j];
    for (int c = 0; c < D; ++c) acc = fmaf(s_g[c], W1[c * D + j], acc);
    float m = silu_f(acc) * W2[j];
    #pragma unroll
    for (int off = 32; off > 0; off >>= 1) m += __shfl_down(m, off);
    if ((j & 63) == 0) s_part[j >> 6] = m;
    __syncthreads();
    if (j == 0) out[g] = s_part[0] + s_part[1] + b2[0];
}

extern "C" void kernel_launch(void* const* d_in, const int* in_sizes, int n_in,
                              void* d_out, int out_size, void* d_ws, size_t ws_size,
                              hipStream_t stream) {
    const float* edge_vec  = (const float*)d_in[0];
    const float* embedding = (const float*)d_in[1];
    const float* phi_W1    = (const float*)d_in[2];
    const float* phi_b1    = (const float*)d_in[3];
    const float* phi_W2    = (const float*)d_in[4];
    const float* phi_b2    = (const float*)d_in[5];
    const float* filt_W    = (const float*)d_in[6];
    const float* filt_b    = (const float*)d_in[7];
    const float* upd_W1    = (const float*)d_in[8];
    const float* upd_b1    = (const float*)d_in[9];
    const float* upd_W2    = (const float*)d_in[10];
    const float* upd_b2    = (const float*)d_in[11];
    const float* out_W1    = (const float*)d_in[12];
    const float* out_b1    = (const float*)d_in[13];
    const float* out_W2    = (const float*)d_in[14];
    const float* out_b2    = (const float*)d_in[15];
    const float* U_W       = (const float*)d_in[16];
    const float* V_W       = (const float*)d_in[17];
    const int* atom_types  = (const int*)d_in[18];
    const int* node_from   = (const int*)d_in[19];
    const int* node_to     = (const int*)d_in[20];
    const int* ngi         = (const int*)d_in[21];
    float* out = (float*)d_out;

    // Workspace layout — identical 19,303,936-float footprint to the passing
    // rounds. sv region is dead after k_uv and is reused for hid.
    float* ws = (float*)d_ws;
    float* phi_tab = ws;                               // 38,400
    float* state   = phi_tab + NATOMS * 384;           // 3,200,000
    float* sv      = state + NNODES * D;               // 9,600,000
    float* gsb     = sv + (size_t)NNODES * 3 * D;      // 65,536
    float* scratch = gsb + NGRAPHS * D;                // 6,400,000-float region
    int*   row_ptr = (int*)scratch;                    // 25,001 ints
    int*   counts  = row_ptr + NNODES + 1;             // 25,000 ints (cursor)
    int*   ety     = counts + NNODES;                  // 250,000 ints
    float* edata   = scratch + 300004;                 // 6,000,000 floats (16B aligned)
    float* UVb     = scratch;                          // phase-2 alias
    float* Vnb     = scratch + NNODES * D;             // phase-2 alias
    float* hid     = sv;                               // phase-3 alias (sv dead)

    k_phi_table<<<NATOMS, 128, 0, stream>>>(embedding, phi_W1, phi_b1, phi_W2, phi_b2, phi_tab);
    k_zero<<<(NGRAPHS * D + 255) / 256, 256, 0, stream>>>(counts, gsb);
    k_hist<<<(NEDGES + 255) / 256, 256, 0, stream>>>(node_to, counts);
    k_scan<<<1, 1024, 0, stream>>>(counts, row_ptr);
    k_pre<<<(NEDGES + 255) / 256, 256, 0, stream>>>(
        edge_vec, node_from, node_to, atom_types, counts, edata, ety);
    k_gather<<<NNODES / GNPB, 128, 0, stream>>>(
        row_ptr, edata, ety, phi_tab, filt_W, filt_b, embedding, atom_types, state, sv);
    k_uv<<<(NNODES + BNUV - 1) / BNUV, 256, 0, stream>>>(sv, U_W, V_W, UVb, Vnb);
    k_mlp1<<<(NNODES + BN1 - 1) / BN1, 256, 0, stream>>>(Vnb, state, upd_W1, upd_b1, hid);
    k_mlp2<<<(NNODES + BN2 - 1) / BN2, 256, 0, stream>>>(hid, state, UVb, upd_W2, upd_b2, ngi, gsb);
    k_out<<<NGRAPHS, 128, 0, stream>>>(gsb, out_W1, out_b1, out_W2, out_b2, out);
}